// Round 15
// baseline (3559.798 us; speedup 1.0000x reference)
//
#include <hip/hip_runtime.h>

// VQ-VAE quantizer. x:[32][64][64][64] f32 NCHW, codebook:[512][64] f32.
// d_out = quantized[8388608] ++ loss[1] ++ hist[32*512], all f32.
//
// DESIGN (round 12): only the argmin INDEX must be bit-exact vs numpy
// (hist thr<1; quantized = gather(idx); loss thr 0.68). Two kernels:
//  K1 vq_prune : MFMA bf16 hi/lo-split scores T~ = S2 - 2*x.e for all
//    (point,code); tracks per-point best idx + a FLAG set whenever any
//    elimination event has |T1-T2| <= MARGIN. Unflagged => approx argmin
//    == exact argmin, guaranteed by the error bound below.
//  K2 vq_finish: unflagged points take K1's idx; flagged points get a
//    wave-cooperative exact 512-code rescan with the r4-verified
//    reference arithmetic (seq __fmaf_rn chain, pairwise S1/S2, two-step
//    rounding, (D,k) lexicographic min = numpy first-min tie-break).
//    Then the usual epilogue (quantized write, loss, hist).
//
// ERROR BOUND: x=xh+xl (xh=trunc16, xl=bf16rne(x-xh)), e likewise.
// dot - [xh.eh + xh.el + xl.eh] per dim <= 2^-13|x||e|;
// sum <= 2^-13 * (1/512)*Sum|x_c| <= 2^-13*96/512 = 2.3e-5 (Sum|x|<=96
// for N(0,1), max over 131072 pts ~74). eps_T = 2*2.3e-5 = 4.6e-5;
// + T-vs-D fp32-snap discrepancy 1.5e-5 -> rigorous margin ~1.1e-4.
// MARGIN = 3e-4 (2.8x). P(flag) ~ margin/meangap(6e-3) ~ 5%.
// RN rounding is monotone, so T-order > MARGIN implies D-order matches.
//
// MFMA LAYOUT SAFETY: A-frag and B-frag are packed with the SAME
// (lane>>4,i)->dim bijection G(h,i)=32s+8h+i on both operands; HW maps
// A[row=lane&15][k=8h+reg] and B[k=8h+reg][col=lane&15] (mirrored), so
// D[m][n] = sum_c x_m[c]e_n[c] for ANY shared intra-lane k-order.
// C/D: col=lane&15, row=4*(lane>>4)+reg (verified, learn_hip m89).
//
// PERF HISTORY: r9 scalar s_load 228us (K$ miss stalls); r10 LDS
// broadcast 336us (16 ds_read_b128/code, LDS inst-throughput); r11 vL1
// broadcast 561us (~20cyc/same-addr load). All broadcast paths >= 4x off
// roofline -> matrix cores.

typedef short bf16x8 __attribute__((ext_vector_type(8)));
typedef float f32x4  __attribute__((ext_vector_type(4)));

#define CDIM   64
#define KCB    512
#define HW     4096
#define NPTS   (32 * HW)          // 131072
#define OUTQ   (32 * CDIM * HW)   // 8388608
#define MARGIN 3.0e-4f

__global__ __launch_bounds__(256) void vq_zero_tail(float* __restrict__ tail, int n) {
    int i = blockIdx.x * 256 + threadIdx.x;
    if (i < n) tail[i] = 0.0f;
}

// numpy pairwise_sum of v[c]^2, n=64 (8-acc unrolled block, pairwise combine)
__device__ __forceinline__ float np_sumsq64(const float* __restrict__ v) {
    float r0 = __fmul_rn(v[0], v[0]), r1 = __fmul_rn(v[1], v[1]);
    float r2 = __fmul_rn(v[2], v[2]), r3 = __fmul_rn(v[3], v[3]);
    float r4 = __fmul_rn(v[4], v[4]), r5 = __fmul_rn(v[5], v[5]);
    float r6 = __fmul_rn(v[6], v[6]), r7 = __fmul_rn(v[7], v[7]);
#pragma unroll
    for (int i = 8; i < 64; i += 8) {
        r0 = __fadd_rn(r0, __fmul_rn(v[i + 0], v[i + 0]));
        r1 = __fadd_rn(r1, __fmul_rn(v[i + 1], v[i + 1]));
        r2 = __fadd_rn(r2, __fmul_rn(v[i + 2], v[i + 2]));
        r3 = __fadd_rn(r3, __fmul_rn(v[i + 3], v[i + 3]));
        r4 = __fadd_rn(r4, __fmul_rn(v[i + 4], v[i + 4]));
        r5 = __fadd_rn(r5, __fmul_rn(v[i + 5], v[i + 5]));
        r6 = __fadd_rn(r6, __fmul_rn(v[i + 6], v[i + 6]));
        r7 = __fadd_rn(r7, __fmul_rn(v[i + 7], v[i + 7]));
    }
    return __fadd_rn(__fadd_rn(__fadd_rn(r0, r1), __fadd_rn(r2, r3)),
                     __fadd_rn(__fadd_rn(r4, r5), __fadd_rn(r6, r7)));
}

__device__ __forceinline__ unsigned short bf16_rne(float f) {
    unsigned u = __float_as_uint(f);
    u += 0x7fffu + ((u >> 16) & 1u);
    return (unsigned short)(u >> 16);
}

// ---------------- K1: MFMA pruner ----------------
// grid 256 blocks x 512 threads; wave w owns 64 consecutive points
// (4 groups of 16); M-blocked 4 groups per B-fragment read.
__global__ __launch_bounds__(512)
__attribute__((amdgpu_waves_per_eu(2, 2)))
void vq_prune(const float* __restrict__ x, const float* __restrict__ cb,
              unsigned* __restrict__ idxflag) {
    __shared__ unsigned short ehi[KCB * CDIM];   // 64 KB, XOR-swizzled rows
    __shared__ unsigned short elo[KCB * CDIM];   // 64 KB
    __shared__ float s2[KCB];                    // 2 KB
    const int tid = threadIdx.x;

    // --- pack codebook to bf16 hi/lo in LDS (swizzle ^((code&7)<<4)) ---
#pragma unroll
    for (int it = 0; it < 8; ++it) {
        int chunk = tid + it * 512;              // 4096 chunks of 8 dims
        int code = chunk >> 3, j = chunk & 7;
        const float* ep = cb + code * CDIM + j * 8;
        unsigned short hh[8], ll[8];
#pragma unroll
        for (int i = 0; i < 8; ++i) {
            float v = ep[i];
            unsigned hb = __float_as_uint(v) & 0xffff0000u;
            hh[i] = (unsigned short)(hb >> 16);
            ll[i] = bf16_rne(v - __uint_as_float(hb));
        }
        unsigned boff = (unsigned)(code * 128 + j * 16) ^ (unsigned)((code & 7) << 4);
        *(bf16x8*)((char*)ehi + boff) = *(bf16x8*)hh;
        *(bf16x8*)((char*)elo + boff) = *(bf16x8*)ll;
    }
    if (tid < KCB) s2[tid] = np_sumsq64(cb + tid * CDIM);
    __syncthreads();

    const int lane = tid & 63, wave = tid >> 6;
    const int l15 = lane & 15, h = lane >> 4;
    const int wbase = blockIdx.x * 512 + wave * 64;   // first point of wave

    // --- load + pack A-fragments: 4 groups x 2 ksteps x {hi,lo} ---
    bf16x8 Ahi[4][2], Alo[4][2];
#pragma unroll
    for (int g = 0; g < 4; ++g) {
        int pt = wbase + g * 16 + l15;
        int b = pt >> 12, p = pt & 4095;
        const float* xb = x + b * (CDIM * HW) + p;
#pragma unroll
        for (int s = 0; s < 2; ++s) {
            unsigned short hh[8], ll[8];
#pragma unroll
            for (int i = 0; i < 8; ++i) {
                float v = xb[(32 * s + 8 * h + i) * HW];  // G(h,i): same map as B
                unsigned hb = __float_as_uint(v) & 0xffff0000u;
                hh[i] = (unsigned short)(hb >> 16);
                ll[i] = bf16_rne(v - __uint_as_float(hb));
            }
            Ahi[g][s] = *(bf16x8*)hh;
            Alo[g][s] = *(bf16x8*)ll;
        }
    }

    float    bestv[4][4], flagf[4][4];
    unsigned bestk[4][4];
#pragma unroll
    for (int g = 0; g < 4; ++g)
#pragma unroll
        for (int r = 0; r < 4; ++r) {
            bestv[g][r] = 3.4e38f; flagf[g][r] = 3.4e38f; bestk[g][r] = 0u;
        }

    // --- 32 col-tiles x 2 ksteps x 3 split-MFMAs x 4 groups ---
    for (int t = 0; t < 32; ++t) {
        f32x4 acc[4];
#pragma unroll
        for (int s = 0; s < 2; ++s) {
            unsigned boff = (unsigned)((t * 16 + l15) * 128 + s * 64 + h * 16)
                            ^ (unsigned)((l15 & 7) << 4);
            bf16x8 Bh = *(bf16x8*)((char*)ehi + boff);
            bf16x8 Bl = *(bf16x8*)((char*)elo + boff);
#pragma unroll
            for (int g = 0; g < 4; ++g) {
                f32x4 c = (s == 0) ? (f32x4)(0.f) : acc[g];
                c = __builtin_amdgcn_mfma_f32_16x16x32_bf16(Ahi[g][s], Bh, c, 0, 0, 0);
                c = __builtin_amdgcn_mfma_f32_16x16x32_bf16(Alo[g][s], Bh, c, 0, 0, 0);
                c = __builtin_amdgcn_mfma_f32_16x16x32_bf16(Ahi[g][s], Bl, c, 0, 0, 0);
                acc[g] = c;
            }
        }
        float s2v = s2[t * 16 + l15];          // code = t*16 + col(lane&15)
        unsigned kk = (unsigned)(t * 16 + l15);
#pragma unroll
        for (int g = 0; g < 4; ++g)
#pragma unroll
            for (int r = 0; r < 4; ++r) {
                float T = __fmaf_rn(-2.f, acc[g][r], s2v);
                float d = T - bestv[g][r];
                flagf[g][r] = fminf(flagf[g][r], fabsf(d) - MARGIN);
                bool lt = T < bestv[g][r];
                bestv[g][r] = lt ? T : bestv[g][r];
                bestk[g][r] = lt ? kk : bestk[g][r];
            }
    }

    // --- cross-lane reduce over the 16 cols in each quadrant + store ---
#pragma unroll
    for (int g = 0; g < 4; ++g) {
        unsigned res[4];
#pragma unroll
        for (int r = 0; r < 4; ++r) {
            float v = bestv[g][r], f = flagf[g][r];
            unsigned k = bestk[g][r];
#pragma unroll
            for (int m = 1; m < 16; m <<= 1) {
                float    vo = __shfl_xor(v, m, 64);
                unsigned ko = (unsigned)__shfl_xor((int)k, m, 64);
                float    fo = __shfl_xor(f, m, 64);
                f = fminf(fminf(f, fo), fabsf(v - vo) - MARGIN);  // merge-event tie check
                bool take = (vo < v) || (vo == v && ko < k);
                v = take ? vo : v;
                k = take ? ko : k;
            }
            res[r] = k | ((f <= 0.f) ? 0x80000000u : 0u);
        }
        if (l15 == 0) {      // lanes 0,16,32,48 write rows 4h..4h+3
            uint4 st = make_uint4(res[0], res[1], res[2], res[3]);
            *(uint4*)(idxflag + wbase + g * 16 + 4 * h) = st;
        }
    }
}

// ---------------- K2: resolve + epilogue ----------------
__global__ __launch_bounds__(256)
__attribute__((amdgpu_waves_per_eu(2, 2)))
void vq_finish(const float* __restrict__ x, const float* __restrict__ cb,
               const unsigned* __restrict__ idxflag, float* __restrict__ out) {
    __shared__ float    s2[KCB];
    __shared__ unsigned hist[KCB];
    const int tid = threadIdx.x;

    for (int k = tid; k < KCB; k += 256) {
        s2[k] = np_sumsq64(cb + k * CDIM);
        hist[k] = 0u;
    }
    __syncthreads();

    const int n = blockIdx.x * 256 + tid;
    const int b = n >> 12, p = n & 4095;
    const int lane = tid & 63;
    const float* xb = x + b * (CDIM * HW) + p;
    float xr[CDIM];
#pragma unroll
    for (int c = 0; c < CDIM; ++c) xr[c] = xb[c * HW];
    const float S1 = np_sumsq64(xr);

    unsigned iw = idxflag[n];
    int bidx = (int)(iw & 0xffffu);
    bool flg = (iw & 0x80000000u) != 0u;

    // --- exact resolution of flagged points (wave-cooperative) ---
    unsigned long long mask = __ballot(flg);
    while (mask) {
        int f = __ffsll((unsigned long long)mask) - 1;
        mask &= mask - 1;
        float xf[CDIM];
#pragma unroll
        for (int c = 0; c < CDIM; ++c) xf[c] = __shfl(xr[c], f, 64);
        float S1f = __shfl(S1, f, 64);
        float bD = 3.4e38f; int bK = 0x7fffffff;
#pragma unroll
        for (int m = 0; m < 8; ++m) {
            int k = lane + m * 64;               // ascending within lane
            const float4* e4 = (const float4*)(cb + k * CDIM);
            float a = 0.f;
#pragma unroll
            for (int c4 = 0; c4 < 16; ++c4) {
                float4 ev = e4[c4];
                a = __fmaf_rn(xf[4 * c4 + 0], ev.x, a);
                a = __fmaf_rn(xf[4 * c4 + 1], ev.y, a);
                a = __fmaf_rn(xf[4 * c4 + 2], ev.z, a);
                a = __fmaf_rn(xf[4 * c4 + 3], ev.w, a);
            }
            float D = __fmaf_rn(-2.f, a, __fadd_rn(S1f, s2[k]));
            bool lt = (D < bD);                  // strict <: lowest k in lane
            bD = lt ? D : bD;
            bK = lt ? k : bK;
        }
#pragma unroll
        for (int m2 = 1; m2 < 64; m2 <<= 1) {    // (D,k) lexicographic
            float Do = __shfl_xor(bD, m2, 64);
            int   Ko = __shfl_xor(bK, m2, 64);
            bool take = (Do < bD) || (Do == bD && Ko < bK);
            bD = take ? Do : bD;
            bK = take ? Ko : bK;
        }
        if (lane == f) bidx = bK;
    }

    atomicAdd(&hist[bidx], 1u);

    // --- epilogue: straight-through write + squared-diff accumulation ---
    const float* e = cb + bidx * CDIM;
    float* ob = out + b * (CDIM * HW) + p;
    float ds = 0.f;
#pragma unroll
    for (int c = 0; c < CDIM; ++c) {
        float q = e[c];
        float d = q - xr[c];
        ds = fmaf(d, d, ds);
        ob[c * HW] = xr[c] + d;                  // x + (q - x), reference rounding
    }

#pragma unroll
    for (int off = 32; off > 0; off >>= 1) ds += __shfl_down(ds, off, 64);
    __shared__ float wsum[4];
    if ((tid & 63) == 0) wsum[tid >> 6] = ds;
    __syncthreads();                             // also orders LDS hist atomics
    if (tid == 0) {
        float s = (wsum[0] + wsum[1]) + (wsum[2] + wsum[3]);
        atomicAdd(out + OUTQ, s * (1.25f / (float)OUTQ));
    }

    float* ho = out + OUTQ + 1 + b * KCB;
    for (int k = tid; k < KCB; k += 256) {
        unsigned cnt = hist[k];
        if (cnt) atomicAdd(ho + k, (float)cnt);
    }
}

extern "C" void kernel_launch(void* const* d_in, const int* in_sizes, int n_in,
                              void* d_out, int out_size, void* d_ws, size_t ws_size,
                              hipStream_t stream) {
    const float* x  = (const float*)d_in[0];
    const float* cb = (const float*)d_in[1];
    float* out = (float*)d_out;
    unsigned* idxflag = (unsigned*)d_ws;         // 131072 * 4B = 512 KB scratch

    const int tail = 1 + 32 * KCB;               // loss + hist
    vq_zero_tail<<<(tail + 255) / 256, 256, 0, stream>>>(out + OUTQ, tail);
    vq_prune<<<256, 512, 0, stream>>>(x, cb, idxflag);
    vq_finish<<<NPTS / 256, 256, 0, stream>>>(x, cb, idxflag, out);
}

// Round 17
// 411.887 us; speedup vs baseline: 8.6427x; 8.6427x over previous
//
#include <hip/hip_runtime.h>

// VQ-VAE quantizer. x:[32][64][64][64] f32 NCHW, codebook:[512][64] f32.
// d_out = quantized[8388608] ++ loss[1] ++ hist[32*512], all f32.
//
// DESIGN (r15 PASSED absmax 0.0 — layout + flagging + rescan verified):
//  K1 vq_prune : MFMA bf16 hi/lo-split scores T~ = S2 - 2*x.e; per point
//    tracks TOP-2 (v1,v2) + argmin k1. Flag iff v2 - v1 <= MARGIN (the
//    minimal sound condition; r15's per-event flagging tripped ~37% on
//    running-best bulk ties -> 48K rescans -> 6.2GB scratch/gather traffic).
//  K2 vq_finish: unflagged -> K1 idx. Flagged -> exact 512-code rescan
//    (bit-identical arithmetic to r4-verified reference emulation), with
//    the flagged point's x staged in a per-wave LDS row (r15's per-lane
//    xf[64] copy doubled VGPR pressure -> scratch spill = the 3.25ms).
//
// ERROR BOUND (unchanged): split-bf16 dot err <= 2.3e-5 per dot; eps_T =
// 4.6e-5; + fp32-snap discrepancy 1.5e-5 -> rigorous ~1.1e-4.
// MARGIN = 3e-4 (2.8x). P(final gap <= MARGIN) ~ 5%.
//
// MFMA LAYOUT (r15-verified on HW): A/B packed with same G(h,i)=32s+8h+i
// bijection; C/D col=lane&15, row=4*(lane>>4)+reg.

typedef short bf16x8 __attribute__((ext_vector_type(8)));
typedef float f32x4  __attribute__((ext_vector_type(4)));

#define CDIM   64
#define KCB    512
#define HW     4096
#define NPTS   (32 * HW)          // 131072
#define OUTQ   (32 * CDIM * HW)   // 8388608
#define MARGIN 3.0e-4f

__global__ __launch_bounds__(256) void vq_zero_tail(float* __restrict__ tail, int n) {
    int i = blockIdx.x * 256 + threadIdx.x;
    if (i < n) tail[i] = 0.0f;
}

// numpy pairwise_sum of v[c]^2, n=64 (8-acc unrolled block, pairwise combine)
__device__ __forceinline__ float np_sumsq64(const float* __restrict__ v) {
    float r0 = __fmul_rn(v[0], v[0]), r1 = __fmul_rn(v[1], v[1]);
    float r2 = __fmul_rn(v[2], v[2]), r3 = __fmul_rn(v[3], v[3]);
    float r4 = __fmul_rn(v[4], v[4]), r5 = __fmul_rn(v[5], v[5]);
    float r6 = __fmul_rn(v[6], v[6]), r7 = __fmul_rn(v[7], v[7]);
#pragma unroll
    for (int i = 8; i < 64; i += 8) {
        r0 = __fadd_rn(r0, __fmul_rn(v[i + 0], v[i + 0]));
        r1 = __fadd_rn(r1, __fmul_rn(v[i + 1], v[i + 1]));
        r2 = __fadd_rn(r2, __fmul_rn(v[i + 2], v[i + 2]));
        r3 = __fadd_rn(r3, __fmul_rn(v[i + 3], v[i + 3]));
        r4 = __fadd_rn(r4, __fmul_rn(v[i + 4], v[i + 4]));
        r5 = __fadd_rn(r5, __fmul_rn(v[i + 5], v[i + 5]));
        r6 = __fadd_rn(r6, __fmul_rn(v[i + 6], v[i + 6]));
        r7 = __fadd_rn(r7, __fmul_rn(v[i + 7], v[i + 7]));
    }
    return __fadd_rn(__fadd_rn(__fadd_rn(r0, r1), __fadd_rn(r2, r3)),
                     __fadd_rn(__fadd_rn(r4, r5), __fadd_rn(r6, r7)));
}

__device__ __forceinline__ unsigned short bf16_rne(float f) {
    unsigned u = __float_as_uint(f);
    u += 0x7fffu + ((u >> 16) & 1u);
    return (unsigned short)(u >> 16);
}

// ---------------- K1: MFMA pruner (top-2 flag) ----------------
__global__ __launch_bounds__(512)
__attribute__((amdgpu_waves_per_eu(2, 2)))
void vq_prune(const float* __restrict__ x, const float* __restrict__ cb,
              unsigned* __restrict__ idxflag) {
    __shared__ unsigned short ehi[KCB * CDIM];   // 64 KB, XOR-swizzled rows
    __shared__ unsigned short elo[KCB * CDIM];   // 64 KB
    __shared__ float s2[KCB];                    // 2 KB
    const int tid = threadIdx.x;

    // --- pack codebook to bf16 hi/lo in LDS (swizzle ^((code&7)<<4)) ---
#pragma unroll
    for (int it = 0; it < 8; ++it) {
        int chunk = tid + it * 512;              // 4096 chunks of 8 dims
        int code = chunk >> 3, j = chunk & 7;
        const float* ep = cb + code * CDIM + j * 8;
        unsigned short hh[8], ll[8];
#pragma unroll
        for (int i = 0; i < 8; ++i) {
            float v = ep[i];
            unsigned hb = __float_as_uint(v) & 0xffff0000u;
            hh[i] = (unsigned short)(hb >> 16);
            ll[i] = bf16_rne(v - __uint_as_float(hb));
        }
        unsigned boff = (unsigned)(code * 128 + j * 16) ^ (unsigned)((code & 7) << 4);
        *(bf16x8*)((char*)ehi + boff) = *(bf16x8*)hh;
        *(bf16x8*)((char*)elo + boff) = *(bf16x8*)ll;
    }
    if (tid < KCB) s2[tid] = np_sumsq64(cb + tid * CDIM);
    __syncthreads();

    const int lane = tid & 63, wave = tid >> 6;
    const int l15 = lane & 15, h = lane >> 4;
    const int wbase = blockIdx.x * 512 + wave * 64;   // first point of wave

    // --- load + pack A-fragments: 4 groups x 2 ksteps x {hi,lo} ---
    bf16x8 Ahi[4][2], Alo[4][2];
#pragma unroll
    for (int g = 0; g < 4; ++g) {
        int pt = wbase + g * 16 + l15;
        int b = pt >> 12, p = pt & 4095;
        const float* xb = x + b * (CDIM * HW) + p;
#pragma unroll
        for (int s = 0; s < 2; ++s) {
            unsigned short hh[8], ll[8];
#pragma unroll
            for (int i = 0; i < 8; ++i) {
                float v = xb[(32 * s + 8 * h + i) * HW];  // G(h,i): same map as B
                unsigned hb = __float_as_uint(v) & 0xffff0000u;
                hh[i] = (unsigned short)(hb >> 16);
                ll[i] = bf16_rne(v - __uint_as_float(hb));
            }
            Ahi[g][s] = *(bf16x8*)hh;
            Alo[g][s] = *(bf16x8*)ll;
        }
    }

    float    v1[4][4], v2[4][4];
    unsigned k1[4][4];
#pragma unroll
    for (int g = 0; g < 4; ++g)
#pragma unroll
        for (int r = 0; r < 4; ++r) {
            v1[g][r] = 3.4e38f; v2[g][r] = 3.4e38f; k1[g][r] = 0u;
        }

    // --- 32 col-tiles x 2 ksteps x 3 split-MFMAs x 4 groups ---
    for (int t = 0; t < 32; ++t) {
        f32x4 acc[4];
#pragma unroll
        for (int s = 0; s < 2; ++s) {
            unsigned boff = (unsigned)((t * 16 + l15) * 128 + s * 64 + h * 16)
                            ^ (unsigned)((l15 & 7) << 4);
            bf16x8 Bh = *(bf16x8*)((char*)ehi + boff);
            bf16x8 Bl = *(bf16x8*)((char*)elo + boff);
#pragma unroll
            for (int g = 0; g < 4; ++g) {
                f32x4 c = (s == 0) ? (f32x4)(0.f) : acc[g];
                c = __builtin_amdgcn_mfma_f32_16x16x32_bf16(Ahi[g][s], Bh, c, 0, 0, 0);
                c = __builtin_amdgcn_mfma_f32_16x16x32_bf16(Alo[g][s], Bh, c, 0, 0, 0);
                c = __builtin_amdgcn_mfma_f32_16x16x32_bf16(Ahi[g][s], Bl, c, 0, 0, 0);
                acc[g] = c;
            }
        }
        float s2v = s2[t * 16 + l15];          // code = t*16 + col(lane&15)
        unsigned kk = (unsigned)(t * 16 + l15);
#pragma unroll
        for (int g = 0; g < 4; ++g)
#pragma unroll
            for (int r = 0; r < 4; ++r) {
                float T = __fmaf_rn(-2.f, acc[g][r], s2v);
                bool lt1 = T < v1[g][r];
                bool lt2 = T < v2[g][r];
                v2[g][r] = lt1 ? v1[g][r] : (lt2 ? T : v2[g][r]);
                v1[g][r] = lt1 ? T : v1[g][r];
                k1[g][r] = lt1 ? kk : k1[g][r];
            }
    }

    // --- cross-lane top-2 merge over the 16 cols in each quadrant + store ---
#pragma unroll
    for (int g = 0; g < 4; ++g) {
        unsigned res[4];
#pragma unroll
        for (int r = 0; r < 4; ++r) {
            float a1 = v1[g][r], a2 = v2[g][r];
            unsigned ak = k1[g][r];
#pragma unroll
            for (int m = 1; m < 16; m <<= 1) {
                float    b1 = __shfl_xor(a1, m, 64);
                float    b2 = __shfl_xor(a2, m, 64);
                unsigned bk = (unsigned)__shfl_xor((int)ak, m, 64);
                float hi  = fmaxf(a1, b1);           // 2nd-best of the two bests
                a2 = fminf(hi, fminf(a2, b2));       // union's second-smallest
                bool take = (b1 < a1) || (b1 == a1 && bk < ak);
                a1 = take ? b1 : a1;
                ak = take ? bk : ak;
            }
            res[r] = ak | ((a2 - a1 <= MARGIN) ? 0x80000000u : 0u);
        }
        if (l15 == 0) {      // lanes 0,16,32,48 write rows 4h..4h+3
            uint4 st = make_uint4(res[0], res[1], res[2], res[3]);
            *(uint4*)(idxflag + wbase + g * 16 + 4 * h) = st;
        }
    }
}

// ---------------- K2: resolve + epilogue ----------------
__global__ __launch_bounds__(256)
__attribute__((amdgpu_waves_per_eu(2, 2)))
void vq_finish(const float* __restrict__ x, const float* __restrict__ cb,
               const unsigned* __restrict__ idxflag, float* __restrict__ out) {
    __shared__ float    s2[KCB];
    __shared__ unsigned hist[KCB];
    __shared__ float    xs[4][CDIM];             // per-wave rescan stage (1 KB)
    const int tid = threadIdx.x;

    for (int k = tid; k < KCB; k += 256) {
        s2[k] = np_sumsq64(cb + k * CDIM);
        hist[k] = 0u;
    }
    __syncthreads();

    const int n = blockIdx.x * 256 + tid;
    const int b = n >> 12, p = n & 4095;
    const int lane = tid & 63, wv = tid >> 6;
    const float* xb = x + b * (CDIM * HW) + p;
    float xr[CDIM];
#pragma unroll
    for (int c = 0; c < CDIM; ++c) xr[c] = xb[c * HW];
    const float S1 = np_sumsq64(xr);

    unsigned iw = idxflag[n];
    int bidx = (int)(iw & 0xffffu);
    bool flg = (iw & 0x80000000u) != 0u;

    // --- exact resolution of flagged points (x staged via per-wave LDS) ---
    unsigned long long mask = __ballot(flg);
    while (mask) {
        int f = __ffsll((unsigned long long)mask) - 1;
        mask &= mask - 1;
        if (lane == f) {
#pragma unroll
            for (int c = 0; c < CDIM; ++c) xs[wv][c] = xr[c];
        }
        asm volatile("s_waitcnt lgkmcnt(0)" ::: "memory");
        __builtin_amdgcn_sched_barrier(0);
        float S1f = __shfl(S1, f, 64);
        volatile const float* xp = xs[wv];       // volatile: no hoist, no re-vectorize
        float bD = 3.4e38f; int bK = 0x7fffffff;
#pragma unroll
        for (int m = 0; m < 8; ++m) {
            int k = lane + m * 64;               // ascending within lane
            const float4* e4 = (const float4*)(cb + k * CDIM);
            float a = 0.f;
#pragma unroll
            for (int c4 = 0; c4 < 16; ++c4) {
                float4 ev = e4[c4];
                a = __fmaf_rn(xp[4 * c4 + 0], ev.x, a);
                a = __fmaf_rn(xp[4 * c4 + 1], ev.y, a);
                a = __fmaf_rn(xp[4 * c4 + 2], ev.z, a);
                a = __fmaf_rn(xp[4 * c4 + 3], ev.w, a);
            }
            float D = __fmaf_rn(-2.f, a, __fadd_rn(S1f, s2[k]));
            bool lt = (D < bD);                  // strict <: lowest k in lane
            bD = lt ? D : bD;
            bK = lt ? k : bK;
        }
#pragma unroll
        for (int m2 = 1; m2 < 64; m2 <<= 1) {    // (D,k) lexicographic
            float Do = __shfl_xor(bD, m2, 64);
            int   Ko = __shfl_xor(bK, m2, 64);
            bool take = (Do < bD) || (Do == bD && Ko < bK);
            bD = take ? Do : bD;
            bK = take ? Ko : bK;
        }
        if (lane == f) bidx = bK;
        __builtin_amdgcn_sched_barrier(0);       // keep xs reads before next overwrite
    }

    atomicAdd(&hist[bidx], 1u);

    // --- epilogue: straight-through write + squared-diff accumulation ---
    const float* e = cb + bidx * CDIM;
    float* ob = out + b * (CDIM * HW) + p;
    float ds = 0.f;
#pragma unroll
    for (int c = 0; c < CDIM; ++c) {
        float q = e[c];
        float d = q - xr[c];
        ds = fmaf(d, d, ds);
        ob[c * HW] = xr[c] + d;                  // x + (q - x), reference rounding
    }

#pragma unroll
    for (int off = 32; off > 0; off >>= 1) ds += __shfl_down(ds, off, 64);
    __shared__ float wsum[4];
    if ((tid & 63) == 0) wsum[tid >> 6] = ds;
    __syncthreads();                             // also orders LDS hist atomics
    if (tid == 0) {
        float s = (wsum[0] + wsum[1]) + (wsum[2] + wsum[3]);
        atomicAdd(out + OUTQ, s * (1.25f / (float)OUTQ));
    }

    float* ho = out + OUTQ + 1 + b * KCB;
    for (int k = tid; k < KCB; k += 256) {
        unsigned cnt = hist[k];
        if (cnt) atomicAdd(ho + k, (float)cnt);
    }
}

extern "C" void kernel_launch(void* const* d_in, const int* in_sizes, int n_in,
                              void* d_out, int out_size, void* d_ws, size_t ws_size,
                              hipStream_t stream) {
    const float* x  = (const float*)d_in[0];
    const float* cb = (const float*)d_in[1];
    float* out = (float*)d_out;
    unsigned* idxflag = (unsigned*)d_ws;         // 131072 * 4B = 512 KB scratch

    const int tail = 1 + 32 * KCB;               // loss + hist
    vq_zero_tail<<<(tail + 255) / 256, 256, 0, stream>>>(out + OUTQ, tail);
    vq_prune<<<256, 512, 0, stream>>>(x, cb, idxflag);
    vq_finish<<<NPTS / 256, 256, 0, stream>>>(x, cb, idxflag, out);
}